// Round 5
// baseline (98.281 us; speedup 1.0000x reference)
//
#include <hip/hip_runtime.h>

// PartitionPadding: ragged [N, D] rows (sorted segment ids) -> dense
// [B, max_atoms, D] zero-padded tensor. Single fused output-centric kernel:
// each block binary-searches the sorted indicator for its molecule's
// [start, end), then streams its 32KB slab segment. Every output element is
// written every call (harness poisons d_out once).
//
// Hot-path structure: blocks are classified as pure-copy (unconditional
// batched loads), pure-pad (zero stores, no loads), or straddle/tail
// (predicated). Loads are explicitly batched into registers before any
// store so 8 x 16B loads are in flight per thread (MLP for HBM latency).

#define BATCH 512
#define UNROLL 8
#define TPB 256
#define APB (TPB * UNROLL / 128)   // atoms spanned per block.x = 16

typedef float f32x4 __attribute__((ext_vector_type(4)));

__global__ void gather_pad_fused(const f32x4* __restrict__ in,
                                 const int* __restrict__ mol,
                                 f32x4* __restrict__ out,
                                 int n, int row4, int nxfull) {
    const int m = blockIdx.y;

    // starts[m], starts[m+1] via lower_bound on the sorted indicator (L2-hot).
    __shared__ int sh[2];
    if (threadIdx.x < 2) {
        const int target = m + threadIdx.x;
        int lo = 0, hi = n;
        while (lo < hi) {
            const int mid = (lo + hi) >> 1;
            if (mol[mid] < target) lo = mid + 1; else hi = mid;
        }
        sh[threadIdx.x] = lo;
    }
    __syncthreads();
    const int s = sh[0];
    const int cnt = sh[1] - sh[0];

    const f32x4* __restrict__ inm = in + (long long)s * 128;
    f32x4* __restrict__ outm = out + (long long)m * row4;

    const int j0 = blockIdx.x * (TPB * UNROLL) + threadIdx.x;
    const int aBegin = blockIdx.x * APB;

    if (blockIdx.x < nxfull) {
        if (aBegin + APB <= cnt) {
            // Pure copy: batch 8 loads, then 8 nt stores.
            f32x4 v[UNROLL];
            #pragma unroll
            for (int u = 0; u < UNROLL; ++u) v[u] = inm[j0 + u * TPB];
            #pragma unroll
            for (int u = 0; u < UNROLL; ++u)
                __builtin_nontemporal_store(v[u], &outm[j0 + u * TPB]);
        } else if (aBegin >= cnt) {
            // Pure pad: no loads.
            #pragma unroll
            for (int u = 0; u < UNROLL; ++u)
                __builtin_nontemporal_store((f32x4)(0.f), &outm[j0 + u * TPB]);
        } else {
            // Straddling block (one per molecule): predicated batch.
            f32x4 v[UNROLL];
            #pragma unroll
            for (int u = 0; u < UNROLL; ++u) {
                const int j = j0 + u * TPB;
                v[u] = (f32x4)(0.f);
                if ((j >> 7) < cnt) v[u] = inm[j];
            }
            #pragma unroll
            for (int u = 0; u < UNROLL; ++u)
                __builtin_nontemporal_store(v[u], &outm[j0 + u * TPB]);
        }
    } else {
        // Tail block: bounds-checked.
        #pragma unroll
        for (int u = 0; u < UNROLL; ++u) {
            const int j = j0 + u * TPB;
            if (j < row4) {
                f32x4 v = (f32x4)(0.f);
                if ((j >> 7) < cnt) v = inm[j];
                __builtin_nontemporal_store(v, &outm[j]);
            }
        }
    }
}

extern "C" void kernel_launch(void* const* d_in, const int* in_sizes, int n_in,
                              void* d_out, int out_size, void* d_ws, size_t ws_size,
                              hipStream_t stream) {
    const float* atom_features = (const float*)d_in[0];
    const int* mol = (const int*)d_in[1];
    float* out = (float*)d_out;

    const int n = in_sizes[1];                 // 65536 atoms
    const int d = in_sizes[0] / n;             // 512 features
    const int max_atoms = out_size / (BATCH * d);
    const int d4 = d / 4;                      // 128
    const int row4 = max_atoms * d4;           // float4s per molecule slab

    const int span = TPB * UNROLL;             // 2048 float4s per block
    const int nx = (row4 + span - 1) / span;
    const int nxfull = row4 / span;

    dim3 grid(nx, BATCH);
    gather_pad_fused<<<grid, TPB, 0, stream>>>(
        (const f32x4*)atom_features, mol, (f32x4*)out, n, row4, nxfull);
}

// Round 6
// 69.149 us; speedup vs baseline: 1.4213x; 1.4213x over previous
//
#include <hip/hip_runtime.h>

// PartitionPadding: ragged [N, D] rows (sorted segment ids) -> dense
// [B, max_atoms, D] zero-padded tensor. Single fused output-centric kernel:
// each block binary-searches the sorted indicator for its molecule's
// [start, end), then streams its slab segment. Every output element is
// written every call (harness poisons d_out once).
//
// R6: identical to the 54.3us R4 kernel EXCEPT plain stores instead of
// nontemporal. R5's counters showed NT stores caused ~1.6x write
// amplification (WRITE_SIZE 274MB vs 173MB output) -> controlled A/B.

#define BATCH 512
#define UNROLL 8
#define TPB 256

typedef float f32x4 __attribute__((ext_vector_type(4)));

__global__ void gather_pad_fused(const f32x4* __restrict__ in,
                                 const int* __restrict__ mol,
                                 f32x4* __restrict__ out,
                                 int n, int row4, int nxfull) {
    const int m = blockIdx.y;

    // starts[m], starts[m+1] via lower_bound on the sorted indicator (L2-hot).
    __shared__ int sh[2];
    if (threadIdx.x < 2) {
        const int target = m + threadIdx.x;
        int lo = 0, hi = n;
        while (lo < hi) {
            const int mid = (lo + hi) >> 1;
            if (mol[mid] < target) lo = mid + 1; else hi = mid;
        }
        sh[threadIdx.x] = lo;
    }
    __syncthreads();
    const int s = sh[0];
    const int cnt = sh[1] - sh[0];

    // Flat within-slab float4 index j = a*128 + dd4  ->  src = in + s*128 + j
    // (atoms of a molecule are contiguous). Only the pad predicate needs a.
    const f32x4* __restrict__ inm = in + (long long)s * 128;
    f32x4* __restrict__ outm = out + (long long)m * row4;

    const int j0 = blockIdx.x * (TPB * UNROLL) + threadIdx.x;
    if (blockIdx.x < nxfull) {
        // Block fully in range: no j bounds checks.
        #pragma unroll
        for (int u = 0; u < UNROLL; ++u) {
            const int j = j0 + u * TPB;
            const int a = j >> 7;            // d4 == 128
            f32x4 v = (f32x4)(0.f);
            if (a < cnt) v = inm[j];         // predicated: pad rows load nothing
            outm[j] = v;
        }
    } else {
        // Tail block: bounds-checked.
        #pragma unroll
        for (int u = 0; u < UNROLL; ++u) {
            const int j = j0 + u * TPB;
            if (j < row4) {
                const int a = j >> 7;
                f32x4 v = (f32x4)(0.f);
                if (a < cnt) v = inm[j];
                outm[j] = v;
            }
        }
    }
}

extern "C" void kernel_launch(void* const* d_in, const int* in_sizes, int n_in,
                              void* d_out, int out_size, void* d_ws, size_t ws_size,
                              hipStream_t stream) {
    const float* atom_features = (const float*)d_in[0];
    const int* mol = (const int*)d_in[1];
    float* out = (float*)d_out;

    const int n = in_sizes[1];                 // 65536 atoms
    const int d = in_sizes[0] / n;             // 512 features
    const int max_atoms = out_size / (BATCH * d);
    const int d4 = d / 4;                      // 128
    const int row4 = max_atoms * d4;           // float4s per molecule slab

    const int span = TPB * UNROLL;             // 2048 float4s per block
    const int nx = (row4 + span - 1) / span;
    const int nxfull = row4 / span;

    dim3 grid(nx, BATCH);
    gather_pad_fused<<<grid, TPB, 0, stream>>>(
        (const f32x4*)atom_features, mol, (f32x4*)out, n, row4, nxfull);
}

// Round 7
// 51.999 us; speedup vs baseline: 1.8900x; 1.3298x over previous
//
#include <hip/hip_runtime.h>

// PartitionPadding: ragged [N, D] rows (sorted segment ids) -> dense
// [B, max_atoms, D] zero-padded tensor.
//
// R7: exact R1 structure (two kernels, ONE float4 per thread — the config
// that measured 61.6us with plain stores) with a single controlled change:
// nontemporal stores. A/B ladder so far:
//   R1 plain,  1/thread : 61.6
//   R6 plain,  8/thread : 69.1   (unroll hurts plain)
//   R4 nt,     8/thread : 54.3   (nt + unroll)
//   R7 nt,     1/thread : predicted ~47-52 if effects additive
// NT avoids L2/L3 write-allocate on the 173MB output stream; 1/thread keeps
// per-wave vmcnt queues shallow and relies on occupancy (8x more blocks)
// for latency hiding.

#define BATCH 512

typedef float f32x4 __attribute__((ext_vector_type(4)));  // native vec for nontemporal builtin

// Kernel 1: find segment starts from the sorted molecule_indicator.
// starts[m] = first index i with mol[i] == m; starts[B] = n.
__global__ void find_starts_kernel(const int* __restrict__ mol, int n,
                                   int* __restrict__ starts, int batch) {
    int i = blockIdx.x * blockDim.x + threadIdx.x;
    if (i >= n) return;
    if (i == 0) {
        starts[mol[0]] = 0;
        starts[batch] = n;
    } else if (mol[i] != mol[i - 1]) {
        starts[mol[i]] = i;
    }
}

// Kernel 2: output-centric gather/pad, one 16B vector per thread.
// Flat within-slab float4 index j = a*128 + dd4 -> src = in + s*128 + j
// (atoms of a molecule are contiguous). Only the pad predicate needs a.
__global__ void gather_pad_kernel(const f32x4* __restrict__ in,
                                  const int* __restrict__ starts,
                                  f32x4* __restrict__ out,
                                  int row4) {
    const int m = blockIdx.y;
    const int s = starts[m];                 // uniform scalar loads
    const int cnt = starts[m + 1] - s;
    const int j = blockIdx.x * blockDim.x + threadIdx.x;
    if (j >= row4) return;
    const int a = j >> 7;                    // d4 == 128
    f32x4 v = (f32x4)(0.f);
    if (a < cnt) v = in[(long long)s * 128 + j];
    __builtin_nontemporal_store(v, &out[(long long)m * row4 + j]);
}

extern "C" void kernel_launch(void* const* d_in, const int* in_sizes, int n_in,
                              void* d_out, int out_size, void* d_ws, size_t ws_size,
                              hipStream_t stream) {
    const float* atom_features = (const float*)d_in[0];
    const int* mol = (const int*)d_in[1];
    float* out = (float*)d_out;

    const int n = in_sizes[1];                 // 65536 atoms
    const int d = in_sizes[0] / n;             // 512 features
    const int max_atoms = out_size / (BATCH * d);
    const int d4 = d / 4;                      // 128
    const int row4 = max_atoms * d4;           // float4s per molecule slab

    int* starts = (int*)d_ws;                  // BATCH+1 ints of scratch

    find_starts_kernel<<<(n + 255) / 256, 256, 0, stream>>>(mol, n, starts, BATCH);

    dim3 grid((row4 + 255) / 256, BATCH);
    gather_pad_kernel<<<grid, 256, 0, stream>>>(
        (const f32x4*)atom_features, starts, (f32x4*)out, row4);
}